// Round 3
// 1590.786 us; speedup vs baseline: 1.0741x; 1.0741x over previous
//
#include <hip/hip_runtime.h>
#include <hip/hip_bf16.h>

typedef __attribute__((ext_vector_type(8))) short short8;
typedef __attribute__((ext_vector_type(4))) float floatx4;

#define Bb 64
#define Ii 48
#define Oo 48
#define Ff 256
#define Hh 256
#define NG 1280      // 5*H
#define KK 512       // 2F (Wx rows) == 2H (Ws rows)
#define CHUNK 80     // packed cols per wg = 5 gates x 16 h
#define NH 16        // h-values per chunk
#define HCHUNKS 16   // 1280/80
#define WORKERS 16   // row-workers; worker w owns rows w, w+16, w+32
#define RING 4       // j-ring depth for S/C state
#define WLDS_STRIDE 520      // 512 + 8 pad
#define WLDS_STRIDE_PRE 264  // 256 + 8 pad

// ---------------- pack / cast kernel ----------------
// Gate-major packing: packed col p = hc*80 + g*16 + hsub <-> orig col
// g*256 + hc*16 + hsub. MFMA output block t == gate t, output col lane == h-sub,
// so the recurrent kernel consumes its accumulators directly (no LDS transpose).
__global__ __launch_bounds__(256) void pack_kernel(
    const float* __restrict__ Wx, const float* __restrict__ Ws,
    const float* __restrict__ x, const float* __restrict__ y,
    __hip_bfloat16* __restrict__ Wxp, __hip_bfloat16* __restrict__ Wsp,
    __hip_bfloat16* __restrict__ xb, __hip_bfloat16* __restrict__ yb) {
  int idx = blockIdx.x * blockDim.x + threadIdx.x;
  int stride = gridDim.x * blockDim.x;
  int total_w = NG * KK;
  for (int t = idx; t < total_w; t += stride) {
    int np = t / KK, k = t % KK;
    int hcp = np / CHUNK;
    int rem = np - hcp * CHUNK;
    int g = rem >> 4;
    int hsub = rem & 15;
    int orig = g * Hh + hcp * NH + hsub;
    Wxp[t] = __float2bfloat16(Wx[k * NG + orig]);
    Wsp[t] = __float2bfloat16(Ws[k * NG + orig]);
  }
  int total_x = Bb * Ii * Ff;
  for (int t = idx; t < total_x; t += stride) {
    int f = t % Ff; int rest = t / Ff; int b = rest % Bb; int i = rest / Bb;
    xb[(i * Bb + b) * Ff + f] = __float2bfloat16(x[(b * Ii + i) * Ff + f]);
    yb[(i * Bb + b) * Ff + f] = __float2bfloat16(y[(b * Oo + i) * Ff + f]);
  }
}

// ---------------- precompute GEMM: Px[i][b][n'], Py[j][b][n'] (packing-agnostic)
__global__ __launch_bounds__(256) void pregemm(
    const __hip_bfloat16* __restrict__ xb, const __hip_bfloat16* __restrict__ yb,
    const __hip_bfloat16* __restrict__ Wxp,
    float* __restrict__ Px, float* __restrict__ Py) {
  __shared__ __hip_bfloat16 Wl[CHUNK * WLDS_STRIDE_PRE];
  int wg = blockIdx.x;
  int isY = wg >= (Ii * HCHUNKS);
  int w = isY ? wg - Ii * HCHUNKS : wg;
  int mblk = w >> 4;
  int hc = w & 15;
  int n0 = hc * CHUNK;
  int koff = isY ? Ff : 0;
  int tid = threadIdx.x;
  for (int idx = tid; idx < CHUNK * (Ff / 8); idx += 256) {
    int cl = idx >> 5;
    int kb = (idx & 31) << 3;
    *(short8*)&Wl[cl * WLDS_STRIDE_PRE + kb] =
        *(const short8*)&Wxp[(n0 + cl) * KK + koff + kb];
  }
  __syncthreads();
  int wave = tid >> 6, lane = tid & 63;
  int lr = lane & 15, q = lane >> 4;
  const __hip_bfloat16* Arow = (isY ? yb : xb) + ((size_t)mblk * Bb + wave * 16 + lr) * Ff;
  floatx4 acc[5];
#pragma unroll
  for (int t = 0; t < 5; t++) acc[t] = (floatx4){0.f, 0.f, 0.f, 0.f};
#pragma unroll
  for (int ks = 0; ks < Ff / 32; ks++) {
    int k = ks * 32 + q * 8;
    short8 a = *(const short8*)(Arow + k);
#pragma unroll
    for (int t = 0; t < 5; t++) {
      short8 bfr = *(const short8*)&Wl[(t * 16 + lr) * WLDS_STRIDE_PRE + k];
      acc[t] = __builtin_amdgcn_mfma_f32_16x16x32_bf16(a, bfr, acc[t], 0, 0, 0);
    }
  }
  float* Pr = (isY ? Py : Px) + (size_t)mblk * Bb * NG + n0;
#pragma unroll
  for (int t = 0; t < 5; t++)
#pragma unroll
    for (int r = 0; r < 4; r++)
      Pr[(wave * 16 + q * 4 + r) * NG + t * 16 + lr] = acc[t][r];
}

// ---------------- coherence helpers (L2-bypassing, no cache-wide fences) ----
__device__ __forceinline__ void wait16(const int* p) {
  while (__hip_atomic_load(p, __ATOMIC_RELAXED, __HIP_MEMORY_SCOPE_AGENT) < HCHUNKS)
    __builtin_amdgcn_s_sleep(1);
}

// 16B bf16 A-fragment via two 8B agent-scope (L1/L2-bypass) loads
__device__ __forceinline__ short8 load8_sc(const __hip_bfloat16* p) {
  const unsigned long long* q = (const unsigned long long*)p;
  union { unsigned long long u[2]; short8 v; } r;
  r.u[0] = __hip_atomic_load(q,     __ATOMIC_RELAXED, __HIP_MEMORY_SCOPE_AGENT);
  r.u[1] = __hip_atomic_load(q + 1, __ATOMIC_RELAXED, __HIP_MEMORY_SCOPE_AGENT);
  return r.v;
}

__device__ __forceinline__ void store_bf16_sc(__hip_bfloat16* p, float f) {
  union { __hip_bfloat16 b; unsigned short u; } cv;
  cv.b = __float2bfloat16(f);
  __hip_atomic_store((unsigned short*)p, cv.u, __ATOMIC_RELAXED, __HIP_MEMORY_SCOPE_AGENT);
}

// ---------------- row-pipelined recurrent kernel ----------------
// PROVEN schedule (round-0): 256 wgs = 16 row-workers x 16 hchunks, 1 wg/CU.
// Worker w processes rows w, w+16, w+32, each j=0..47 left-to-right. Per cell,
// waits (tid0 only):
//   done[i-1][j]   (vertical data dep: S row above + C above)
//   done[i][j-1]   (sibling hchunks' S slices of own row)
//   done[i+1][j-4] (WAR: depth-4 j-ring slot reuse)
// State exchanged via agent-scope loads/stores; Px/Py/Wsp stay L2-resident.
// DELTA vs round-0 (the only change): gate-major packing lets the elementwise
// phase consume the MFMA accumulators directly (acc[t][ra] = gate t,
// b = wave*16+q*4+ra, h = h0+(lane&15)) -> Dl/Pxl LDS staging and one barrier
// per cell are deleted; Px slice lives in registers.
__global__ __launch_bounds__(256) void lstm_row(
    const float* __restrict__ Px, const float* __restrict__ Py,
    const float* __restrict__ bias, const __hip_bfloat16* __restrict__ Wsp,
    __hip_bfloat16* __restrict__ Sring, float* __restrict__ Cring,
    const __hip_bfloat16* __restrict__ Szero,
    float* __restrict__ out, int* __restrict__ done) {
  __shared__ __hip_bfloat16 Wl[CHUNK * WLDS_STRIDE];  // 83,200 B (only LDS use)
  int wg = blockIdx.x;
  int worker = wg >> 4;
  int hc = wg & 15;
  int n0 = hc * CHUNK;
  int h0 = hc * NH;
  int tid = threadIdx.x;
  int wave = tid >> 6, lane = tid & 63;
  int lr = lane & 15, q = lane >> 4;
  const int brow = wave * 16 + q * 4;   // elementwise b-rows: brow..brow+3
  const int hme = h0 + lr;              // this thread's h
  const size_t BH = (size_t)Bb * Hh;

  // persistent Ws slice: 80 packed cols x 512 k
  for (int idx = tid; idx < CHUNK * (KK / 8); idx += 256) {
    int cl = idx >> 6;
    int kb = (idx & 63) << 3;
    *(short8*)&Wl[cl * WLDS_STRIDE + kb] = *(const short8*)&Wsp[(n0 + cl) * KK + kb];
  }
  float bv[5];
#pragma unroll
  for (int g = 0; g < 5; g++) bv[g] = bias[g * Hh + hme];

#pragma unroll 1
  for (int rr = 0; rr < 3; rr++) {
    int i = worker + rr * WORKERS;
    // ---- per-row: Px slice -> registers (reused for 48 cells) ----
    float pxv[4][5];
#pragma unroll
    for (int ra = 0; ra < 4; ra++)
#pragma unroll
      for (int g = 0; g < 5; g++)
        pxv[ra][g] = Px[((size_t)i * Bb + (brow + ra)) * NG + n0 + g * 16 + lr];

    float cvreg[4];   // register-carried horizontal C state c(i, j-1)
#pragma unroll
    for (int it = 0; it < 4; it++) cvreg[it] = 0.f;

#pragma unroll 1
    for (int j = 0; j < Oo; j++) {
      // ---- prefetch Py slice (immutable, L2-cacheable) before the waits ----
      const float* PyR = Py + (size_t)j * Bb * NG + n0;
      float pyv[4][5];
#pragma unroll
      for (int ra = 0; ra < 4; ra++)
#pragma unroll
        for (int g = 0; g < 5; g++)
          pyv[ra][g] = PyR[(size_t)(brow + ra) * NG + g * 16 + lr];

      // ---- waits: tid0 polls, barrier broadcasts ----
      if (tid == 0) {
        if (i > 0) wait16(done + (i - 1) * Oo + j);
        if (j > 0) wait16(done + i * Oo + (j - 1));
        if (i + 1 < Ii && j >= RING) wait16(done + (i + 1) * Oo + (j - RING));
      }
      __syncthreads();   // also covers initial Wl staging (rr==0, j==0)

      // ---- state pointers (depth-4 j-ring) ----
      const __hip_bfloat16* Sv = (i > 0)
          ? Sring + ((size_t)(i - 1) * RING + (j & (RING - 1))) * BH : Szero;
      const __hip_bfloat16* Sh = (j > 0)
          ? Sring + ((size_t)i * RING + ((j - 1) & (RING - 1))) * BH : Szero;
      __hip_bfloat16* Sout = Sring + ((size_t)i * RING + (j & (RING - 1))) * BH;
      float* Cout = Cring + ((size_t)i * RING + (j & (RING - 1))) * BH;

      // ---- C-above loads (agent scope), overlap with GEMM ----
      float chv[4];
      if (i > 0) {
        const float* Chp = Cring + ((size_t)(i - 1) * RING + (j & (RING - 1))) * BH;
#pragma unroll
        for (int ra = 0; ra < 4; ra++)
          chv[ra] = __hip_atomic_load(&Chp[(size_t)(brow + ra) * Hh + hme],
                                      __ATOMIC_RELAXED, __HIP_MEMORY_SCOPE_AGENT);
      } else {
#pragma unroll
        for (int ra = 0; ra < 4; ra++) chv[ra] = 0.f;
      }

      // ---- GEMM: (64 x 512) @ (512 x 80); A = [S_above | S_left] ----
      const __hip_bfloat16* SvR = Sv + (size_t)(wave * 16 + lr) * Hh;
      const __hip_bfloat16* ShR = Sh + (size_t)(wave * 16 + lr) * Hh;
      floatx4 acc[5];
#pragma unroll
      for (int t = 0; t < 5; t++) acc[t] = (floatx4){0.f, 0.f, 0.f, 0.f};
#pragma unroll
      for (int ks = 0; ks < KK / 32; ks++) {
        int k = ks * 32 + q * 8;
        short8 a = (k < Hh) ? load8_sc(SvR + k) : load8_sc(ShR + (k - Hh));
#pragma unroll
        for (int t = 0; t < 5; t++) {
          short8 bfr = *(const short8*)&Wl[(t * 16 + lr) * WLDS_STRIDE + k];
          acc[t] = __builtin_amdgcn_mfma_f32_16x16x32_bf16(a, bfr, acc[t], 0, 0, 0);
        }
      }

      // ---- elementwise LSTM update directly from accumulators ----
      // acc[t][ra] = (gate t, b = brow+ra, h = hme)
#pragma unroll
      for (int ra = 0; ra < 4; ra++) {
        int b = brow + ra;
        float pre[5];
#pragma unroll
        for (int g = 0; g < 5; g++)
          pre[g] = acc[g][ra] + pxv[ra][g] + pyv[ra][g] + bv[g];
        float ig = 1.f / (1.f + __expf(-pre[0]));
        float fg = 1.f / (1.f + __expf(-pre[1]));
        float og = 1.f / (1.f + __expf(-pre[2]));
        float lg = 1.f / (1.f + __expf(-pre[3]));
        float gg = 1.f - 2.f / (__expf(2.f * pre[4]) + 1.f);   // tanh
        float cn = fg * (lg * chv[ra] + (1.f - lg) * cvreg[ra]) + ig * gg;
        float tc = 1.f - 2.f / (__expf(2.f * cn) + 1.f);
        float sn = og * tc;
        cvreg[ra] = cn;                      // horizontal C for cell (i, j+1)
        __hip_atomic_store(&Cout[(size_t)b * Hh + hme], cn,
                           __ATOMIC_RELAXED, __HIP_MEMORY_SCOPE_AGENT);
        store_bf16_sc(&Sout[(size_t)b * Hh + hme], sn);
        out[(((size_t)i * Oo + j) * Bb + b) * Hh + hme] = sn;
      }
      // ---- publish: drain wg stores (vmcnt(0) implied by barrier), bump flag
      __syncthreads();
      if (tid == 0) atomicAdd(done + i * Oo + j, 1);
    }
  }
}

// ---------------- host ----------------
extern "C" void kernel_launch(void* const* d_in, const int* in_sizes, int n_in,
                              void* d_out, int out_size, void* d_ws, size_t ws_size,
                              hipStream_t stream) {
  const float* x    = (const float*)d_in[0];
  const float* y    = (const float*)d_in[1];
  const float* Wx   = (const float*)d_in[2];
  const float* Ws   = (const float*)d_in[3];
  const float* bias = (const float*)d_in[4];
  float* out = (float*)d_out;

  char* ws = (char*)d_ws;
  size_t off = 0;
  auto alloc = [&](size_t bytes) -> void* {
    void* p = ws + off;
    off += (bytes + 255) & ~(size_t)255;
    return p;
  };
  __hip_bfloat16* Wxp = (__hip_bfloat16*)alloc((size_t)NG * KK * 2);
  __hip_bfloat16* Wsp = (__hip_bfloat16*)alloc((size_t)NG * KK * 2);
  __hip_bfloat16* xb  = (__hip_bfloat16*)alloc((size_t)Ii * Bb * Ff * 2);
  __hip_bfloat16* yb  = (__hip_bfloat16*)alloc((size_t)Oo * Bb * Ff * 2);
  float* Px = (float*)alloc((size_t)Ii * Bb * NG * 4);
  float* Py = (float*)alloc((size_t)Oo * Bb * NG * 4);
  __hip_bfloat16* Sring = (__hip_bfloat16*)alloc((size_t)Ii * RING * Bb * Hh * 2);
  float* Cring = (float*)alloc((size_t)Ii * RING * Bb * Hh * 4);
  char* zbase = ws + off;
  __hip_bfloat16* Szero = (__hip_bfloat16*)alloc((size_t)Bb * Hh * 2);
  int*   done = (int*)alloc((size_t)Ii * Oo * 4);
  size_t zBytes = (size_t)((ws + off) - zbase);

  // only the zero-buffer + flags need zeroing (ring slots are written before
  // any read per the dependency order)
  hipMemsetAsync(zbase, 0, zBytes, stream);

  hipLaunchKernelGGL(pack_kernel, dim3(512), dim3(256), 0, stream,
                     Wx, Ws, x, y, Wxp, Wsp, xb, yb);
  hipLaunchKernelGGL(pregemm, dim3(2 * Ii * HCHUNKS), dim3(256), 0, stream,
                     xb, yb, Wxp, Px, Py);

  void* args[] = {(void*)&Px, (void*)&Py, (void*)&bias, (void*)&Wsp,
                  (void*)&Sring, (void*)&Cring, (void*)&Szero,
                  (void*)&out, (void*)&done};
  hipLaunchCooperativeKernel((void*)lstm_row, dim3(WORKERS * HCHUNKS), dim3(256),
                             args, 0, stream);
}